// Round 11
// baseline (63.734 us; speedup 1.0000x reference)
//
#include <hip/hip_runtime.h>
#include <stdint.h>

#define HASH_MASK 524287u
#define PRIME1 2654435761u
#define PRIME2 805459861u

// Output: [B][32][256][256] f32, channel c = 2*l + f.
// Block = 1024 threads = 4 rows x 256 cols of one image; 1 px/thread.
// Grid = B*64 = 512 blocks = 2 blocks/CU (full 2048 thr/CU).
// Levels 0..11 staged in LDS per 4-row block; levels 12..15 gathered direct.
// R11 change: fine gathers OVERLAP the fill/barrier —
//   - levels 12,13 loads issued BEFORE __syncthreads (the barrier's memory
//     fence stops the compiler sinking them; they fly during fill drain)
//   - levels 14,15 loads issued right after the barrier (fly during the
//     LDS-interp pass, which runs on the lgkm pipe)
//   - both consumed at the end.
// Model: ~2.4 cyc per unique divergent 64B line per CU; lines/px:
// fill ~4 + fine 16 + stores ~2 -> floor ~44-48 us.

__global__ __launch_bounds__(1024, 8) void lia_hashgrid_kernel(
    const float* __restrict__ x0,        // [B]
    const float* __restrict__ y0,        // [B]
    const float* __restrict__ tables,    // [T][2]
    const uint32_t* __restrict__ seeds,  // [16]
    const float* __restrict__ level_N,   // [16]
    const int* __restrict__ tile_p,      // scalar
    float* __restrict__ out)             // [B][32][65536]
{
    __shared__ float2 lds[6400];         // 51.2 KB; worst-case strips 0..11

    const int bid = blockIdx.x;
    const int b   = bid >> 6;            // 0..7
    const int i0  = (bid & 63) << 2;     // block's first row
    const int tid = threadIdx.x;
    const int j   = tid & 255;
    const int r   = tid >> 8;            // 0..3
    const int i   = i0 + r;

    const float inv_tile = 1.0f / (float)(*tile_p);   // 1/1024, exact
    const float xb  = x0[b];                           // block-uniform
    const float py0 = (float)i0 + y0[b];               // block-uniform
    const float px = (float)j + xb;
    const float py = (float)i + y0[b];

    const float2* __restrict__ tab2 = (const float2*)tables;
    float* outp = out + (size_t)b * 32u * 65536u + (size_t)(i * 256 + j);

    // ---- fine levels 12,13: hashes + loads issued BEFORE the fill ----
    float fxA, fyA, fxB, fyB;
    float2 a00, a10, a01, a11, b00, b10, b01, b11;
    {
        const float sA = level_N[12] * inv_tile;
        const float xnA = px * sA, ynA = py * sA;
        const int ixA = (int)xnA, iyA = (int)ynA;
        fxA = xnA - (float)ixA; fyA = ynA - (float)iyA;
        const uint32_t hxA0 = (uint32_t)ixA * PRIME1, hxA1 = hxA0 + PRIME1;
        const uint32_t hyA0 = (uint32_t)iyA * PRIME2, hyA1 = hyA0 + PRIME2;
        const uint32_t sdA = seeds[12];
        a00 = tab2[(hxA0 ^ hyA0 ^ sdA) & HASH_MASK];
        a10 = tab2[(hxA1 ^ hyA0 ^ sdA) & HASH_MASK];
        a01 = tab2[(hxA0 ^ hyA1 ^ sdA) & HASH_MASK];
        a11 = tab2[(hxA1 ^ hyA1 ^ sdA) & HASH_MASK];

        const float sB = level_N[13] * inv_tile;
        const float xnB = px * sB, ynB = py * sB;
        const int ixB = (int)xnB, iyB = (int)ynB;
        fxB = xnB - (float)ixB; fyB = ynB - (float)iyB;
        const uint32_t hxB0 = (uint32_t)ixB * PRIME1, hxB1 = hxB0 + PRIME1;
        const uint32_t hyB0 = (uint32_t)iyB * PRIME2, hyB1 = hyB0 + PRIME2;
        const uint32_t sdB = seeds[13];
        b00 = tab2[(hxB0 ^ hyB0 ^ sdB) & HASH_MASK];
        b10 = tab2[(hxB1 ^ hyB0 ^ sdB) & HASH_MASK];
        b01 = tab2[(hxB0 ^ hyB1 ^ sdB) & HASH_MASK];
        b11 = tab2[(hxB1 ^ hyB1 ^ sdB) & HASH_MASK];
    }

    // ---- pass 1: cooperative LDS fill of levels 0..11 strips ----
    {
        int off = 0;
        #pragma unroll
        for (int l = 0; l < 12; ++l) {
            const float s = level_N[l] * inv_tile;
            const uint32_t sd = seeds[l];
            const int X0 = (int)(xb * s);
            const int NX = (int)((xb + 255.0f) * s) - X0 + 2;
            const int Y0 = (int)(py0 * s);
            const int NY = (int)((py0 + 3.0f) * s) - Y0 + 2;
            const int cells = NY * NX;
            for (int idx = tid; idx < cells; idx += 1024) {
                const int row = idx / NX;          // NX block-uniform
                const int col = idx - row * NX;
                const uint32_t h = ((uint32_t)(X0 + col) * PRIME1
                                  ^ (uint32_t)(Y0 + row) * PRIME2 ^ sd) & HASH_MASK;
                lds[off + idx] = tab2[h];
            }
            off += cells;
        }
    }
    __syncthreads();   // memory fence: 12/13 loads above stay above

    // ---- fine levels 14,15: loads issued here, fly during LDS interp ----
    float fxC, fyC, fxD, fyD;
    float2 c00, c10, c01, c11, d00, d10, d01, d11;
    {
        const float sC = level_N[14] * inv_tile;
        const float xnC = px * sC, ynC = py * sC;
        const int ixC = (int)xnC, iyC = (int)ynC;
        fxC = xnC - (float)ixC; fyC = ynC - (float)iyC;
        const uint32_t hxC0 = (uint32_t)ixC * PRIME1, hxC1 = hxC0 + PRIME1;
        const uint32_t hyC0 = (uint32_t)iyC * PRIME2, hyC1 = hyC0 + PRIME2;
        const uint32_t sdC = seeds[14];
        c00 = tab2[(hxC0 ^ hyC0 ^ sdC) & HASH_MASK];
        c10 = tab2[(hxC1 ^ hyC0 ^ sdC) & HASH_MASK];
        c01 = tab2[(hxC0 ^ hyC1 ^ sdC) & HASH_MASK];
        c11 = tab2[(hxC1 ^ hyC1 ^ sdC) & HASH_MASK];

        const float sD = level_N[15] * inv_tile;
        const float xnD = px * sD, ynD = py * sD;
        const int ixD = (int)xnD, iyD = (int)ynD;
        fxD = xnD - (float)ixD; fyD = ynD - (float)iyD;
        const uint32_t hxD0 = (uint32_t)ixD * PRIME1, hxD1 = hxD0 + PRIME1;
        const uint32_t hyD0 = (uint32_t)iyD * PRIME2, hyD1 = hyD0 + PRIME2;
        const uint32_t sdD = seeds[15];
        d00 = tab2[(hxD0 ^ hyD0 ^ sdD) & HASH_MASK];
        d10 = tab2[(hxD1 ^ hyD0 ^ sdD) & HASH_MASK];
        d01 = tab2[(hxD0 ^ hyD1 ^ sdD) & HASH_MASK];
        d11 = tab2[(hxD1 ^ hyD1 ^ sdD) & HASH_MASK];
    }

    // ---- pass 2: interpolate levels 0..11 from LDS ----
    {
        int off = 0;
        #pragma unroll
        for (int l = 0; l < 12; ++l) {
            const float s = level_N[l] * inv_tile;
            const int X0 = (int)(xb * s);
            const int NX = (int)((xb + 255.0f) * s) - X0 + 2;
            const int Y0 = (int)(py0 * s);
            const int NY = (int)((py0 + 3.0f) * s) - Y0 + 2;

            const float xn = px * s;
            const int ix = (int)xn;
            const float fx = xn - (float)ix;
            const float yn = py * s;
            const int iy = (int)yn;
            const float fy = yn - (float)iy;

            const int c = off + (iy - Y0) * NX + (ix - X0);
            const float2 f00 = lds[c];
            const float2 f10 = lds[c + 1];
            const float2 f01 = lds[c + NX];
            const float2 f11 = lds[c + NX + 1];

            const float gx = 1.0f - fx, gy = 1.0f - fy;
            const float w00 = gx * gy, w10 = fx * gy;
            const float w01 = gx * fy, w11 = fx * fy;
            const float e0 = w00 * f00.x + w10 * f10.x + w01 * f01.x + w11 * f11.x;
            const float e1 = w00 * f00.y + w10 * f10.y + w01 * f01.y + w11 * f11.y;
            __builtin_nontemporal_store(e0, outp + (size_t)(2 * l) * 65536u);
            __builtin_nontemporal_store(e1, outp + (size_t)(2 * l + 1) * 65536u);
            off += NY * NX;
        }
    }

    // ---- consume fine levels ----
    #define FINISH(l, FX, FY, f00, f10, f01, f11)                              \
    {                                                                          \
        const float gx = 1.0f - FX, gy = 1.0f - FY;                            \
        const float w00 = gx * gy, w10 = FX * gy;                              \
        const float w01 = gx * FY, w11 = FX * FY;                              \
        const float e0 = w00 * f00.x + w10 * f10.x + w01 * f01.x + w11 * f11.x;\
        const float e1 = w00 * f00.y + w10 * f10.y + w01 * f01.y + w11 * f11.y;\
        __builtin_nontemporal_store(e0, outp + (size_t)(2 * (l)) * 65536u);    \
        __builtin_nontemporal_store(e1, outp + (size_t)(2 * (l) + 1) * 65536u);\
    }
    FINISH(12, fxA, fyA, a00, a10, a01, a11)
    FINISH(13, fxB, fyB, b00, b10, b01, b11)
    FINISH(14, fxC, fyC, c00, c10, c01, c11)
    FINISH(15, fxD, fyD, d00, d10, d01, d11)
    #undef FINISH
}

extern "C" void kernel_launch(void* const* d_in, const int* in_sizes, int n_in,
                              void* d_out, int out_size, void* d_ws, size_t ws_size,
                              hipStream_t stream) {
    const float*    x0      = (const float*)d_in[0];
    const float*    y0      = (const float*)d_in[1];
    const float*    tables  = (const float*)d_in[2];
    const uint32_t* seeds   = (const uint32_t*)d_in[3];
    const float*    level_N = (const float*)d_in[4];
    const int*      tile_p  = (const int*)d_in[6];   // complete_tile_size
    float*          out     = (float*)d_out;

    const int B = in_sizes[0];                 // 8
    const int n_blocks = B * 64;               // 512 blocks x 16 waves = 8192 waves

    lia_hashgrid_kernel<<<n_blocks, 1024, 0, stream>>>(
        x0, y0, tables, seeds, level_N, tile_p, out);
}

// Round 12
// 58.396 us; speedup vs baseline: 1.0914x; 1.0914x over previous
//
#include <hip/hip_runtime.h>
#include <stdint.h>

#define HASH_MASK 524287u
#define PRIME1 2654435761u
#define PRIME2 805459861u

// Output: [B][32][256][256] f32, channel c = 2*l + f.
// Block = 1024 threads = 4 rows x 256 cols of one image; 1 px/thread.
// Grid = B*64 = 512 blocks = 8192 waves = exactly 2 blocks/CU (full 2048 thr).
// Levels 0..11 staged in LDS once per 4-row block (strips <= 6400 float2),
// levels 12..15 (cell pitch >= 2px, fully random) gathered directly.
// REVERT of R11: keeping gather/fill/store phases COMPACT is essential —
// stretching fine-gather live ranges across the fill (R11) raised
// FETCH 32->57MB / WRITE 65->78MB (table exactly fills the 4MiB XCD L2;
// any added concurrent-stream pressure evicts it) and cost +9%.
// Model: ~2.5 cyc per unique divergent 64B line per CU; lines/px:
// fill ~5.5 + fine 16 + stores 2 -> this kernel sits at that service wall.

#define HASHES(l, h00, h10, h01, h11, FX, FY)                          \
    float FX, FY; uint32_t h00, h10, h01, h11;                         \
    {                                                                  \
        const float s_ = level_N[l] * inv_tile;                        \
        const float xn_ = px * s_, yn_ = py * s_;                      \
        const int ix_ = (int)xn_, iy_ = (int)yn_;   /* coords >= 0 */  \
        FX = xn_ - (float)ix_; FY = yn_ - (float)iy_;                  \
        const uint32_t hx0_ = (uint32_t)ix_ * PRIME1, hx1_ = hx0_ + PRIME1; \
        const uint32_t hy0_ = (uint32_t)iy_ * PRIME2, hy1_ = hy0_ + PRIME2; \
        const uint32_t sd_ = seeds[l];                                 \
        h00 = (hx0_ ^ hy0_ ^ sd_) & HASH_MASK;                         \
        h10 = (hx1_ ^ hy0_ ^ sd_) & HASH_MASK;                         \
        h01 = (hx0_ ^ hy1_ ^ sd_) & HASH_MASK;                         \
        h11 = (hx1_ ^ hy1_ ^ sd_) & HASH_MASK;                         \
    }

#define LOADS(h00, h10, h01, h11, f00, f10, f01, f11)                  \
    const float2 f00 = tab2[h00], f10 = tab2[h10],                     \
                 f01 = tab2[h01], f11 = tab2[h11];

#define STOREL(l, FX, FY, f00, f10, f01, f11)                          \
    {                                                                  \
        const float gx_ = 1.0f - FX, gy_ = 1.0f - FY;                  \
        const float w00_ = gx_ * gy_, w10_ = FX * gy_;                 \
        const float w01_ = gx_ * FY,  w11_ = FX * FY;                  \
        const float e0_ = w00_ * f00.x + w10_ * f10.x + w01_ * f01.x + w11_ * f11.x; \
        const float e1_ = w00_ * f00.y + w10_ * f10.y + w01_ * f01.y + w11_ * f11.y; \
        __builtin_nontemporal_store(e0_, outp + (size_t)(2 * (l)) * 65536u);     \
        __builtin_nontemporal_store(e1_, outp + (size_t)(2 * (l) + 1) * 65536u); \
    }

#define PAIR(la, lb)                                                   \
    {                                                                  \
        HASHES(la, a00, a10, a01, a11, fxa, fya)                       \
        HASHES(lb, b00, b10, b01, b11, fxb, fyb)                       \
        LOADS(a00, a10, a01, a11, fa00, fa10, fa01, fa11)              \
        LOADS(b00, b10, b01, b11, fb00, fb10, fb01, fb11)              \
        STOREL(la, fxa, fya, fa00, fa10, fa01, fa11)                   \
        STOREL(lb, fxb, fyb, fb00, fb10, fb01, fb11)                   \
    }

__global__ __launch_bounds__(1024, 8) void lia_hashgrid_kernel(
    const float* __restrict__ x0,        // [B]
    const float* __restrict__ y0,        // [B]
    const float* __restrict__ tables,    // [T][2]
    const uint32_t* __restrict__ seeds,  // [16]
    const float* __restrict__ level_N,   // [16]
    const int* __restrict__ tile_p,      // scalar
    float* __restrict__ out)             // [B][32][65536]
{
    __shared__ float2 lds[6400];         // 51.2 KB; worst-case strips 0..11

    const int bid = blockIdx.x;
    const int b   = bid >> 6;            // 0..7
    const int i0  = (bid & 63) << 2;     // block's first row
    const int tid = threadIdx.x;
    const int j   = tid & 255;
    const int r   = tid >> 8;            // 0..3
    const int i   = i0 + r;

    const float inv_tile = 1.0f / (float)(*tile_p);   // 1/1024, exact
    const float xb  = x0[b];                           // block-uniform
    const float py0 = (float)i0 + y0[b];               // block-uniform
    const float px = (float)j + xb;
    const float py = (float)i + y0[b];

    const float2* __restrict__ tab2 = (const float2*)tables;
    float* outp = out + (size_t)b * 32u * 65536u + (size_t)(i * 256 + j);

    // ---- pass 1: cooperative LDS fill of levels 0..11 strips ----
    {
        int off = 0;
        #pragma unroll
        for (int l = 0; l < 12; ++l) {
            const float s = level_N[l] * inv_tile;
            const uint32_t sd = seeds[l];
            const int X0 = (int)(xb * s);
            const int NX = (int)((xb + 255.0f) * s) - X0 + 2;
            const int Y0 = (int)(py0 * s);
            const int NY = (int)((py0 + 3.0f) * s) - Y0 + 2;
            const int cells = NY * NX;
            for (int idx = tid; idx < cells; idx += 1024) {
                const int row = idx / NX;          // NX block-uniform
                const int col = idx - row * NX;
                const uint32_t h = ((uint32_t)(X0 + col) * PRIME1
                                  ^ (uint32_t)(Y0 + row) * PRIME2 ^ sd) & HASH_MASK;
                lds[off + idx] = tab2[h];
            }
            off += cells;
        }
    }
    __syncthreads();

    // ---- pass 2: interpolate levels 0..11 from LDS ----
    {
        int off = 0;
        #pragma unroll
        for (int l = 0; l < 12; ++l) {
            const float s = level_N[l] * inv_tile;
            const int X0 = (int)(xb * s);
            const int NX = (int)((xb + 255.0f) * s) - X0 + 2;
            const int Y0 = (int)(py0 * s);
            const int NY = (int)((py0 + 3.0f) * s) - Y0 + 2;

            const float xn = px * s;
            const int ix = (int)xn;
            const float fx = xn - (float)ix;
            const float yn = py * s;
            const int iy = (int)yn;
            const float fy = yn - (float)iy;

            const int c = off + (iy - Y0) * NX + (ix - X0);
            const float2 f00 = lds[c];
            const float2 f10 = lds[c + 1];
            const float2 f01 = lds[c + NX];
            const float2 f11 = lds[c + NX + 1];

            const float gx = 1.0f - fx, gy = 1.0f - fy;
            const float w00 = gx * gy, w10 = fx * gy;
            const float w01 = gx * fy, w11 = fx * fy;
            const float e0 = w00 * f00.x + w10 * f10.x + w01 * f01.x + w11 * f11.x;
            const float e1 = w00 * f00.y + w10 * f10.y + w01 * f01.y + w11 * f11.y;
            __builtin_nontemporal_store(e0, outp + (size_t)(2 * l) * 65536u);
            __builtin_nontemporal_store(e1, outp + (size_t)(2 * l + 1) * 65536u);
            off += NY * NX;
        }
    }

    // ---- fine levels 12..15: direct random gathers (clustered pairs) ----
    PAIR(12, 13)
    PAIR(14, 15)
}

extern "C" void kernel_launch(void* const* d_in, const int* in_sizes, int n_in,
                              void* d_out, int out_size, void* d_ws, size_t ws_size,
                              hipStream_t stream) {
    const float*    x0      = (const float*)d_in[0];
    const float*    y0      = (const float*)d_in[1];
    const float*    tables  = (const float*)d_in[2];
    const uint32_t* seeds   = (const uint32_t*)d_in[3];
    const float*    level_N = (const float*)d_in[4];
    const int*      tile_p  = (const int*)d_in[6];   // complete_tile_size
    float*          out     = (float*)d_out;

    const int B = in_sizes[0];                 // 8
    const int n_blocks = B * 64;               // 512 blocks x 16 waves = 8192 waves

    lia_hashgrid_kernel<<<n_blocks, 1024, 0, stream>>>(
        x0, y0, tables, seeds, level_N, tile_p, out);
}